// Round 10
// baseline (185.286 us; speedup 1.0000x reference)
//
#include <hip/hip_runtime.h>
#include <hip/hip_bf16.h>
#include <stdint.h>

#define BATCH  2
#define SEQ    2048
#define DMODEL 1024
#define NHEAD  16
#define DHEAD  64

typedef unsigned short u16;
typedef __attribute__((ext_vector_type(8))) short bf16x8;
typedef __attribute__((ext_vector_type(4))) float f32x4;

__device__ __forceinline__ u16 f2bf(float x) {
    union { float f; uint32_t u; } v; v.f = x;
    uint32_t r = v.u + 0x7fffu + ((v.u >> 16) & 1u);
    return (u16)(r >> 16);
}

__device__ __forceinline__ float bf2f(u16 x) {
    union { uint32_t u; float f; } v; v.u = (uint32_t)x << 16; return v.f;
}

__device__ __forceinline__ uint32_t pk2bf(float a, float b) {
    __hip_bfloat162 h = __float22bfloat162_rn(make_float2(a, b));
    return *(uint32_t*)&h;
}

__device__ __forceinline__ void gload_lds16(const void* g, void* l) {
    __builtin_amdgcn_global_load_lds(
        (const __attribute__((address_space(1))) uint32_t*)(uintptr_t)g,
        (__attribute__((address_space(3))) uint32_t*)(uintptr_t)l,
        16, 0, 0);
}

__device__ __forceinline__ f32x4 mfma16(bf16x8 a, bf16x8 b, f32x4 c) {
    return __builtin_amdgcn_mfma_f32_16x16x32_bf16(a, b, c, 0, 0, 0);
}

// ---------------------------------------------------------------------------
// f32 -> bf16 conversion for 3 activations + 4 weights (grid.y = segment)
// ---------------------------------------------------------------------------
__global__ __launch_bounds__(256) void cvt7_kernel(
    const float* s0, const float* s1, const float* s2, const float* s3,
    const float* s4, const float* s5, const float* s6,
    u16* d0, u16* d1, u16* d2, u16* d3, u16* d4, u16* d5, u16* d6)
{
    const float* s; u16* d; size_t n;
    switch (blockIdx.y) {
        case 0: s = s0; d = d0; n = (size_t)BATCH * SEQ * DMODEL; break;
        case 1: s = s1; d = d1; n = (size_t)BATCH * SEQ * DMODEL; break;
        case 2: s = s2; d = d2; n = (size_t)BATCH * SEQ * DMODEL; break;
        case 3: s = s3; d = d3; n = (size_t)DMODEL * DMODEL; break;
        case 4: s = s4; d = d4; n = (size_t)DMODEL * DMODEL; break;
        case 5: s = s5; d = d5; n = (size_t)DMODEL * DMODEL; break;
        default: s = s6; d = d6; n = (size_t)DMODEL * DMODEL; break;
    }
    size_t i = ((size_t)blockIdx.x * 256 + threadIdx.x) * 8;
    if (i >= n) return;
    float4 a = *(const float4*)(s + i);
    float4 b = *(const float4*)(s + i + 4);
    union { uint4 v; u16 e[8]; } u;
    u.e[0] = f2bf(a.x); u.e[1] = f2bf(a.y); u.e[2] = f2bf(a.z); u.e[3] = f2bf(a.w);
    u.e[4] = f2bf(b.x); u.e[5] = f2bf(b.y); u.e[6] = f2bf(b.z); u.e[7] = f2bf(b.w);
    *(uint4*)(d + i) = u.v;
}

// ---------------------------------------------------------------------------
// Shared 128x128 BT-GEMM core (m97 structure): C = A (MxK) * B^T (NxK row-major)
// ---------------------------------------------------------------------------
__device__ __forceinline__ void gemm_core_128(
    const u16* __restrict__ A, const u16* __restrict__ Bm, int K,
    int brow, int bcol, u16* As, u16* Bs, f32x4 (&acc)[4][4])
{
    const int tid  = threadIdx.x;
    const int lane = tid & 63;
    const int wr   = ((tid >> 6) >> 1) * 64;
    const int wc   = ((tid >> 6) & 1) * 64;
    const int srow = tid >> 2;
    const int scol = (tid & 3) * 8;
    const int fr   = lane & 15;
    const int fk   = (lane >> 4) * 8;

    for (int k0 = 0; k0 < K; k0 += 32) {
        gload_lds16(A  + (size_t)(brow + srow) * K + k0 + scol,       As + srow * 32 + scol);
        gload_lds16(A  + (size_t)(brow + 64 + srow) * K + k0 + scol,  As + (64 + srow) * 32 + scol);
        gload_lds16(Bm + (size_t)(bcol + srow) * K + k0 + scol,       Bs + srow * 32 + scol);
        gload_lds16(Bm + (size_t)(bcol + 64 + srow) * K + k0 + scol,  Bs + (64 + srow) * 32 + scol);
        __syncthreads();
        bf16x8 af[4], bfv[4];
        #pragma unroll
        for (int i = 0; i < 4; ++i) {
            af[i]  = *(const bf16x8*)(As + (wr + i * 16 + fr) * 32 + fk);
            bfv[i] = *(const bf16x8*)(Bs + (wc + i * 16 + fr) * 32 + fk);
        }
        #pragma unroll
        for (int am = 0; am < 4; ++am)
            #pragma unroll
            for (int bn = 0; bn < 4; ++bn)
                acc[am][bn] = mfma16(af[am], bfv[bn], acc[am][bn]);
        __syncthreads();
    }
}

// QKV projection: z selects (X, W, out).
// Q scale folds 1/sqrt(dk) AND log2(e) so attention can use exp2 directly.
__global__ __launch_bounds__(256) void gemm_qkv_kernel(
    const u16* __restrict__ Xq, const u16* __restrict__ Xk, const u16* __restrict__ Xv,
    const u16* __restrict__ Wq, const u16* __restrict__ Wk, const u16* __restrict__ Wv,
    u16* __restrict__ Qo, u16* __restrict__ Ko, u16* __restrict__ Vo,
    int M, int Nn, int K)
{
    __shared__ u16 As[128 * 32];
    __shared__ u16 Bs[128 * 32];
    const int z = blockIdx.z;
    const u16* A  = (z == 0) ? Xq : (z == 1) ? Xk : Xv;
    const u16* Bm = (z == 0) ? Wq : (z == 1) ? Wk : Wv;
    u16* D        = (z == 0) ? Qo : (z == 1) ? Ko : Vo;
    const float scale = (z == 0) ? 0.18033688011112042f : 1.0f;  // 0.125*log2(e)

    const int brow = blockIdx.y * 128;
    const int bcol = blockIdx.x * 128;
    f32x4 acc[4][4];
    #pragma unroll
    for (int am = 0; am < 4; ++am)
        #pragma unroll
        for (int bn = 0; bn < 4; ++bn)
            acc[am][bn] = (f32x4){0.f, 0.f, 0.f, 0.f};

    gemm_core_128(A, Bm, K, brow, bcol, As, Bs, acc);

    const int lane = threadIdx.x & 63;
    const int wr = ((threadIdx.x >> 6) >> 1) * 64;
    const int wc = ((threadIdx.x >> 6) & 1) * 64;
    const int fr = lane & 15;
    const int fj4 = (lane >> 4) * 4;
    #pragma unroll
    for (int am = 0; am < 4; ++am)
        #pragma unroll
        for (int bn = 0; bn < 4; ++bn)
            #pragma unroll
            for (int j = 0; j < 4; ++j) {
                int row = brow + wr + am * 16 + fj4 + j;
                int col = bcol + wc + bn * 16 + fr;
                D[(size_t)row * Nn + col] = f2bf(acc[am][bn][j] * scale);
            }
}

// Output projection + bias + residual, fp32 out
__global__ __launch_bounds__(256) void gemm_out_kernel(
    const u16* __restrict__ A, const u16* __restrict__ Bm,
    const float* __restrict__ bias, const float* __restrict__ resid,
    float* __restrict__ D, int M, int Nn, int K)
{
    __shared__ u16 As[128 * 32];
    __shared__ u16 Bs[128 * 32];
    const int brow = blockIdx.y * 128;
    const int bcol = blockIdx.x * 128;
    f32x4 acc[4][4];
    #pragma unroll
    for (int am = 0; am < 4; ++am)
        #pragma unroll
        for (int bn = 0; bn < 4; ++bn)
            acc[am][bn] = (f32x4){0.f, 0.f, 0.f, 0.f};

    gemm_core_128(A, Bm, K, brow, bcol, As, Bs, acc);

    const int lane = threadIdx.x & 63;
    const int wr = ((threadIdx.x >> 6) >> 1) * 64;
    const int wc = ((threadIdx.x >> 6) & 1) * 64;
    const int fr = lane & 15;
    const int fj4 = (lane >> 4) * 4;
    #pragma unroll
    for (int am = 0; am < 4; ++am)
        #pragma unroll
        for (int bn = 0; bn < 4; ++bn)
            #pragma unroll
            for (int j = 0; j < 4; ++j) {
                int row = brow + wr + am * 16 + fj4 + j;
                int col = bcol + wc + bn * 16 + fr;
                D[(size_t)row * Nn + col] = acc[am][bn][j] + bias[col] + resid[(size_t)row * Nn + col];
            }
}

// ---------------------------------------------------------------------------
// V transpose: V[b][n][h*64+d] -> Vt[bh][d][n]  (LDS-tiled, 64x64 tiles)
// ---------------------------------------------------------------------------
__global__ __launch_bounds__(256) void vtrans_kernel(
    const u16* __restrict__ V, u16* __restrict__ Vt)
{
    __shared__ u16 T[64][66];
    const int tid = threadIdx.x;
    const int bh  = blockIdx.y;
    const int kv0 = blockIdx.x * 64;
    const size_t rowbase = (size_t)(bh >> 4) * SEQ;
    const int colbase = (bh & 15) * DHEAD;

    {
        const int r = tid >> 2;
        const int c = (tid & 3) * 16;
        const u16* src = V + (rowbase + kv0 + r) * DMODEL + colbase + c;
        uint4 a = *(const uint4*)(src);
        uint4 b = *(const uint4*)(src + 8);
        uint32_t* dst = (uint32_t*)&T[r][c];
        dst[0] = a.x; dst[1] = a.y; dst[2] = a.z; dst[3] = a.w;
        dst[4] = b.x; dst[5] = b.y; dst[6] = b.z; dst[7] = b.w;
    }
    __syncthreads();
    {
        const int d = tid >> 2;
        const int c = (tid & 3) * 16;
        union { uint4 v; u16 e[8]; } o0, o1;
        #pragma unroll
        for (int j = 0; j < 8; ++j) o0.e[j] = T[c + j][d];
        #pragma unroll
        for (int j = 0; j < 8; ++j) o1.e[j] = T[c + 8 + j][d];
        u16* dst = Vt + (size_t)bh * DHEAD * SEQ + (size_t)d * SEQ + kv0 + c;
        *(uint4*)(dst) = o0.v;
        *(uint4*)(dst + 8) = o1.v;
    }
}

// ---------------------------------------------------------------------------
// Flash attention, deferred softmax + swapped QK^T + KV-SPLIT:
// grid 1024 = 32 bh x 16 q-tiles x 2 kv-halves -> 4 blocks/CU (4 barrier
// domains, r8's staging-duplication avoided: each block stages only its own
// kv half). Partial (O bf16, l f32) written unnormalized; combined by add
// in combine_kernel (deferred softmax has no cross-tile dependency).
// K LDS-staged (dbuf, XOR-swizzled); V direct from L2-resident Vt.
// ---------------------------------------------------------------------------
__global__ __launch_bounds__(256, 4) void attn_kernel(
    const u16* __restrict__ Qb, const u16* __restrict__ Kb, const u16* __restrict__ Vt,
    u16* __restrict__ Opart, float* __restrict__ lpart)
{
    __shared__ u16 Ks[2][64 * 64];   // [kv][d], chunk-swizzled
    __shared__ u16 Ps[128 * 72];

    const int tid  = threadIdx.x;
    const int lane = tid & 63;
    const int wave = tid >> 6;

    // bijective XCD swizzle: 1024 blocks, 8 XCDs -> 128 blocks/XCD = 4 heads
    const int lin  = blockIdx.x;
    const int nlin = (lin & 7) * 128 + (lin >> 3);
    const int bh   = nlin >> 5;          // 32 (b,h) pairs
    const int rem  = nlin & 31;
    const int qblk = rem >> 1;           // 16 q-tiles of 128 rows
    const int half = rem & 1;            // kv half

    const size_t rowbase = (size_t)(bh >> 4) * SEQ;
    const int colbase = (bh & 15) * DHEAD;
    const int q0 = qblk * 128;
    const int kvbase = half * (SEQ / 2);
    const int fr  = lane & 15;
    const int g   = lane >> 4;
    const int fk  = g * 8;
    const int fj4 = g * 4;
    const int qw  = wave * 32;

    const u16* Kh = Kb + rowbase * DMODEL + colbase;   // rows: kv, stride DMODEL
    const u16* Vh = Vt + (size_t)bh * DHEAD * SEQ;     // rows: d,  stride SEQ

    // staging decomposition: linear LDS dest + inverse-swizzled global source
    const int sr  = tid >> 3;
    const int sc  = tid & 7;
    const int scs = (sc ^ (sr & 7)) << 3;   // source col, u16 units
    const int sdst = sr * 64 + sc * 8;      // linear LDS dest, u16 units

    // Q fragments hoisted (1/sqrt(dk)*log2e folded into Q projection)
    bf16x8 qf[2][2];
    #pragma unroll
    for (int am = 0; am < 2; ++am)
        #pragma unroll
        for (int kc = 0; kc < 2; ++kc)
            qf[am][kc] = *(const bf16x8*)(Qb + (rowbase + q0 + qw + am * 16 + fr) * DMODEL
                                             + colbase + kc * 32 + fk);

    f32x4 oacc[2][4];
    float lsum[2];
    #pragma unroll
    for (int am = 0; am < 2; ++am) {
        #pragma unroll
        for (int dn = 0; dn < 4; ++dn) oacc[am][dn] = (f32x4){0.f, 0.f, 0.f, 0.f};
        lsum[am] = 0.f;
    }

    // prologue: stage K tile 0 of this half into buffer 0
    gload_lds16(Kh + (size_t)(kvbase + sr)      * DMODEL + scs, &Ks[0][sdst]);
    gload_lds16(Kh + (size_t)(kvbase + 32 + sr) * DMODEL + scs, &Ks[0][2048 + sdst]);
    __syncthreads();

    int buf = 0;
    for (int kv0 = kvbase; kv0 < kvbase + SEQ / 2; kv0 += 64) {
        const int kvn = kv0 + 64;
        if (kvn < kvbase + SEQ / 2) {   // prefetch next K tile into buf^1
            gload_lds16(Kh + (size_t)(kvn + sr)      * DMODEL + scs, &Ks[buf ^ 1][sdst]);
            gload_lds16(Kh + (size_t)(kvn + 32 + sr) * DMODEL + scs, &Ks[buf ^ 1][2048 + sdst]);
        }
        const u16* K0 = &Ks[buf][0];

        // S^T = K * Q^T (swapped): sacc[am][bn][j] = S[kv=bn*16+fj4+j][q=qw+am*16+fr]
        f32x4 sacc[2][4];
        #pragma unroll
        for (int am = 0; am < 2; ++am)
            #pragma unroll
            for (int bn = 0; bn < 4; ++bn)
                sacc[am][bn] = (f32x4){0.f, 0.f, 0.f, 0.f};
        __builtin_amdgcn_s_setprio(1);
        #pragma unroll
        for (int bn = 0; bn < 4; ++bn) {
            bf16x8 kf0 = *(const bf16x8*)(K0 + (bn * 16 + fr) * 64 + (((g)     ^ (fr & 7)) << 3));
            bf16x8 kf1 = *(const bf16x8*)(K0 + (bn * 16 + fr) * 64 + (((4 + g) ^ (fr & 7)) << 3));
            sacc[0][bn] = mfma16(kf0, qf[0][0], sacc[0][bn]);
            sacc[0][bn] = mfma16(kf1, qf[0][1], sacc[0][bn]);
            sacc[1][bn] = mfma16(kf0, qf[1][0], sacc[1][bn]);
            sacc[1][bn] = mfma16(kf1, qf[1][1], sacc[1][bn]);
        }
        __builtin_amdgcn_s_setprio(0);

        // issue V fragment loads from global now: softmax hides the L2 latency
        bf16x8 vf[4][2];
        #pragma unroll
        for (int dn = 0; dn < 4; ++dn)
            #pragma unroll
            for (int kc = 0; kc < 2; ++kc)
                vf[dn][kc] = *(const bf16x8*)(Vh + (size_t)(dn * 16 + fr) * SEQ
                                                 + kv0 + kc * 32 + fk);

        // deferred softmax: P = exp2(S'); lane-local l; packed bf16 + b64 store
        #pragma unroll
        for (int am = 0; am < 2; ++am) {
            float lacc = 0.f;
            #pragma unroll
            for (int bn = 0; bn < 4; ++bn) {
                float p0 = exp2f(sacc[am][bn][0]);
                float p1 = exp2f(sacc[am][bn][1]);
                float p2 = exp2f(sacc[am][bn][2]);
                float p3 = exp2f(sacc[am][bn][3]);
                uint2 w;
                w.x = pk2bf(p0, p1);
                w.y = pk2bf(p2, p3);
                *(uint2*)(Ps + (qw + am * 16 + fr) * 72 + bn * 16 + fj4) = w;
                lacc += (p0 + p1) + (p2 + p3);
            }
            lsum[am] += lacc;
        }

        // O += P * V  (Ps per-wave-private; lgkmcnt ordering only)
        bf16x8 pf[2][2];
        #pragma unroll
        for (int am = 0; am < 2; ++am)
            #pragma unroll
            for (int kc = 0; kc < 2; ++kc)
                pf[am][kc] = *(const bf16x8*)(Ps + (qw + am * 16 + fr) * 72 + kc * 32 + fk);
        __builtin_amdgcn_s_setprio(1);
        #pragma unroll
        for (int dn = 0; dn < 4; ++dn) {
            oacc[0][dn] = mfma16(pf[0][0], vf[dn][0], oacc[0][dn]);
            oacc[0][dn] = mfma16(pf[0][1], vf[dn][1], oacc[0][dn]);
            oacc[1][dn] = mfma16(pf[1][0], vf[dn][0], oacc[1][dn]);
            oacc[1][dn] = mfma16(pf[1][1], vf[dn][1], oacc[1][dn]);
        }
        __builtin_amdgcn_s_setprio(0);

        __syncthreads();   // drains K prefetch + protects buf swap
        buf ^= 1;
    }

    // l partial: sum across the 4 g-groups (same fr); lane g==0 writes
    #pragma unroll
    for (int am = 0; am < 2; ++am) {
        float l = lsum[am];
        l += __shfl_xor(l, 16);
        l += __shfl_xor(l, 32);
        if (g == 0)
            lpart[nlin * 128 + qw + am * 16 + fr] = l;
    }

    // O partial (unnormalized, bf16)
    u16* Op = Opart + (size_t)nlin * 128 * 64;
    #pragma unroll
    for (int am = 0; am < 2; ++am)
        #pragma unroll
        for (int dn = 0; dn < 4; ++dn)
            #pragma unroll
            for (int j = 0; j < 4; ++j)
                Op[(qw + am * 16 + fj4 + j) * 64 + dn * 16 + fr] =
                    f2bf(oacc[am][dn][j]);
}

// ---------------------------------------------------------------------------
// Combine: AO = (O0 + O1) / (l0 + l1), bf16 out. 512 blocks (bh, qblk).
// ---------------------------------------------------------------------------
__global__ __launch_bounds__(256) void combine_kernel(
    const u16* __restrict__ Opart, const float* __restrict__ lpart,
    u16* __restrict__ AO)
{
    const int c   = blockIdx.x;          // bh*16 + qblk
    const int bh  = c >> 4;
    const int qblk = c & 15;
    const int p0  = c * 2;               // = bh*32 + qblk*2 (half=0)
    const int t   = threadIdx.x;
    const int q   = t >> 1;              // 0..127
    const int d0  = (t & 1) * 32;

    const size_t rowbase = (size_t)(bh >> 4) * SEQ;
    const int colbase = (bh & 15) * DHEAD;

    const float inv = 1.f / (lpart[p0 * 128 + q] + lpart[(p0 + 1) * 128 + q]);

    const u16* O0 = Opart + ((size_t)p0 * 128 + q) * 64 + d0;
    const u16* O1 = O0 + 128 * 64;
    u16* dst = AO + (rowbase + qblk * 128 + q) * DMODEL + colbase + d0;

    #pragma unroll
    for (int i = 0; i < 32; i += 8) {
        union { bf16x8 v; u16 e[8]; } a, b, o;
        a.v = *(const bf16x8*)(O0 + i);
        b.v = *(const bf16x8*)(O1 + i);
        #pragma unroll
        for (int j = 0; j < 8; ++j)
            o.e[j] = f2bf((bf2f(a.e[j]) + bf2f(b.e[j])) * inv);
        *(bf16x8*)(dst + i) = o.v;
    }
}

// ---------------------------------------------------------------------------
extern "C" void kernel_launch(void* const* d_in, const int* in_sizes, int n_in,
                              void* d_out, int out_size, void* d_ws, size_t ws_size,
                              hipStream_t stream)
{
    const float* q_f  = (const float*)d_in[0];
    const float* k_f  = (const float*)d_in[1];
    const float* v_f  = (const float*)d_in[2];
    const float* Wq_f = (const float*)d_in[3];
    const float* Wk_f = (const float*)d_in[4];
    const float* Wv_f = (const float*)d_in[5];
    const float* Wo_f = (const float*)d_in[6];
    const float* bo_f = (const float*)d_in[7];

    char* ws = (char*)d_ws;
    const size_t ACT = (size_t)BATCH * SEQ * DMODEL * sizeof(u16);   // 8 MB
    const size_t WSZ = (size_t)DMODEL * DMODEL * sizeof(u16);        // 2 MB
    u16* Xq  = (u16*)(ws);
    u16* Xk  = (u16*)(ws + ACT);
    u16* Xv  = (u16*)(ws + 2 * ACT);
    u16* Wqb = (u16*)(ws + 3 * ACT);
    u16* Wkb = (u16*)(ws + 3 * ACT + WSZ);
    u16* Wvb = (u16*)(ws + 3 * ACT + 2 * WSZ);
    u16* Wob = (u16*)(ws + 3 * ACT + 3 * WSZ);
    u16* Qb  = (u16*)(ws + 3 * ACT + 4 * WSZ);
    u16* Kb  = (u16*)(ws + 4 * ACT + 4 * WSZ);
    u16* Vb  = (u16*)(ws + 5 * ACT + 4 * WSZ);
    u16* AO  = (u16*)(ws + 6 * ACT + 4 * WSZ);   // total 7*ACT + 4*WSZ = 64 MB
    u16* Vt  = Xq;                 // alias: Xq dead after gemm_qkv
    u16* Opart = Xk;               // alias: Xk+Xv dead after gemm_qkv (16 MB)
    float* lpart = (float*)Wqb;    // alias: Wqb dead after gemm_qkv (512 KB)

    const int M = BATCH * SEQ;      // 4096
    const int Nn = DMODEL;          // 1024
    const int K = DMODEL;           // 1024

    cvt7_kernel<<<dim3(2048, 7, 1), 256, 0, stream>>>(
        q_f, k_f, v_f, Wq_f, Wk_f, Wv_f, Wo_f,
        Xq, Xk, Xv, Wqb, Wkb, Wvb, Wob);

    gemm_qkv_kernel<<<dim3(Nn / 128, M / 128, 3), 256, 0, stream>>>(
        Xq, Xk, Xv, Wqb, Wkb, Wvb, Qb, Kb, Vb, M, Nn, K);

    vtrans_kernel<<<dim3(SEQ / 64, BATCH * NHEAD, 1), 256, 0, stream>>>(Vb, Vt);

    attn_kernel<<<dim3(1024, 1, 1), 256, 0, stream>>>(Qb, Kb, Vt, Opart, lpart);

    combine_kernel<<<dim3(512, 1, 1), 256, 0, stream>>>(Opart, lpart, AO);

    gemm_out_kernel<<<dim3(Nn / 128, M / 128, 1), 256, 0, stream>>>(
        AO, Wob, bo_f, q_f, (float*)d_out, M, Nn, K);
}

// Round 11
// 159.358 us; speedup vs baseline: 1.1627x; 1.1627x over previous
//
#include <hip/hip_runtime.h>
#include <hip/hip_bf16.h>
#include <stdint.h>

#define BATCH  2
#define SEQ    2048
#define DMODEL 1024
#define NHEAD  16
#define DHEAD  64

typedef unsigned short u16;
typedef __attribute__((ext_vector_type(8))) short bf16x8;
typedef __attribute__((ext_vector_type(4))) float f32x4;

__device__ __forceinline__ u16 f2bf(float x) {
    union { float f; uint32_t u; } v; v.f = x;
    uint32_t r = v.u + 0x7fffu + ((v.u >> 16) & 1u);
    return (u16)(r >> 16);
}

__device__ __forceinline__ uint32_t pk2bf(float a, float b) {
    __hip_bfloat162 h = __float22bfloat162_rn(make_float2(a, b));
    return *(uint32_t*)&h;
}

__device__ __forceinline__ void gload_lds16(const void* g, void* l) {
    __builtin_amdgcn_global_load_lds(
        (const __attribute__((address_space(1))) uint32_t*)(uintptr_t)g,
        (__attribute__((address_space(3))) uint32_t*)(uintptr_t)l,
        16, 0, 0);
}

__device__ __forceinline__ f32x4 mfma16(bf16x8 a, bf16x8 b, f32x4 c) {
    return __builtin_amdgcn_mfma_f32_16x16x32_bf16(a, b, c, 0, 0, 0);
}

// ---------------------------------------------------------------------------
// f32 -> bf16 conversion for 3 activations + 4 weights (grid.y = segment)
// ---------------------------------------------------------------------------
__global__ __launch_bounds__(256) void cvt7_kernel(
    const float* s0, const float* s1, const float* s2, const float* s3,
    const float* s4, const float* s5, const float* s6,
    u16* d0, u16* d1, u16* d2, u16* d3, u16* d4, u16* d5, u16* d6)
{
    const float* s; u16* d; size_t n;
    switch (blockIdx.y) {
        case 0: s = s0; d = d0; n = (size_t)BATCH * SEQ * DMODEL; break;
        case 1: s = s1; d = d1; n = (size_t)BATCH * SEQ * DMODEL; break;
        case 2: s = s2; d = d2; n = (size_t)BATCH * SEQ * DMODEL; break;
        case 3: s = s3; d = d3; n = (size_t)DMODEL * DMODEL; break;
        case 4: s = s4; d = d4; n = (size_t)DMODEL * DMODEL; break;
        case 5: s = s5; d = d5; n = (size_t)DMODEL * DMODEL; break;
        default: s = s6; d = d6; n = (size_t)DMODEL * DMODEL; break;
    }
    size_t i = ((size_t)blockIdx.x * 256 + threadIdx.x) * 8;
    if (i >= n) return;
    float4 a = *(const float4*)(s + i);
    float4 b = *(const float4*)(s + i + 4);
    union { uint4 v; u16 e[8]; } u;
    u.e[0] = f2bf(a.x); u.e[1] = f2bf(a.y); u.e[2] = f2bf(a.z); u.e[3] = f2bf(a.w);
    u.e[4] = f2bf(b.x); u.e[5] = f2bf(b.y); u.e[6] = f2bf(b.z); u.e[7] = f2bf(b.w);
    *(uint4*)(d + i) = u.v;
}

// ---------------------------------------------------------------------------
// 64x128 BT-GEMM core: C = A (MxK) * B^T (NxK row-major), tile 64 rows x
// 128 cols, BK=32. 4 waves = 4 N-quadrants of 32. Doubles blocks/CU vs the
// 128^2 core (12 KB LDS/block) - these GEMM shapes are occupancy-bound.
// ---------------------------------------------------------------------------
__device__ __forceinline__ void gemm_core_64x128(
    const u16* __restrict__ A, const u16* __restrict__ Bm, int K,
    int brow, int bcol, u16* As, u16* Bs, f32x4 (&acc)[4][2])
{
    const int tid  = threadIdx.x;
    const int lane = tid & 63;
    const int wc   = (tid >> 6) * 32;
    const int srow = tid >> 2;
    const int scol = (tid & 3) * 8;
    const int fr   = lane & 15;
    const int fk   = (lane >> 4) * 8;

    for (int k0 = 0; k0 < K; k0 += 32) {
        gload_lds16(A  + (size_t)(brow + srow) * K + k0 + scol,       As + srow * 32 + scol);
        gload_lds16(Bm + (size_t)(bcol + srow) * K + k0 + scol,       Bs + srow * 32 + scol);
        gload_lds16(Bm + (size_t)(bcol + 64 + srow) * K + k0 + scol,  Bs + (64 + srow) * 32 + scol);
        __syncthreads();
        bf16x8 af[4], bfv[2];
        #pragma unroll
        for (int i = 0; i < 4; ++i)
            af[i]  = *(const bf16x8*)(As + (i * 16 + fr) * 32 + fk);
        #pragma unroll
        for (int i = 0; i < 2; ++i)
            bfv[i] = *(const bf16x8*)(Bs + (wc + i * 16 + fr) * 32 + fk);
        #pragma unroll
        for (int am = 0; am < 4; ++am)
            #pragma unroll
            for (int bn = 0; bn < 2; ++bn)
                acc[am][bn] = mfma16(af[am], bfv[bn], acc[am][bn]);
        __syncthreads();
    }
}

// QKV projection: z selects (X, W, out).
// Q scale folds 1/sqrt(dk) AND log2(e) so attention can use exp2 directly.
__global__ __launch_bounds__(256) void gemm_qkv_kernel(
    const u16* __restrict__ Xq, const u16* __restrict__ Xk, const u16* __restrict__ Xv,
    const u16* __restrict__ Wq, const u16* __restrict__ Wk, const u16* __restrict__ Wv,
    u16* __restrict__ Qo, u16* __restrict__ Ko, u16* __restrict__ Vo,
    int M, int Nn, int K)
{
    __shared__ u16 As[64 * 32];
    __shared__ u16 Bs[128 * 32];
    const int z = blockIdx.z;
    const u16* A  = (z == 0) ? Xq : (z == 1) ? Xk : Xv;
    const u16* Bm = (z == 0) ? Wq : (z == 1) ? Wk : Wv;
    u16* D        = (z == 0) ? Qo : (z == 1) ? Ko : Vo;
    const float scale = (z == 0) ? 0.18033688011112042f : 1.0f;  // 0.125*log2(e)

    const int brow = blockIdx.y * 64;
    const int bcol = blockIdx.x * 128;
    f32x4 acc[4][2];
    #pragma unroll
    for (int am = 0; am < 4; ++am)
        #pragma unroll
        for (int bn = 0; bn < 2; ++bn)
            acc[am][bn] = (f32x4){0.f, 0.f, 0.f, 0.f};

    gemm_core_64x128(A, Bm, K, brow, bcol, As, Bs, acc);

    const int lane = threadIdx.x & 63;
    const int wc = (threadIdx.x >> 6) * 32;
    const int fr = lane & 15;
    const int fj4 = (lane >> 4) * 4;
    #pragma unroll
    for (int am = 0; am < 4; ++am)
        #pragma unroll
        for (int bn = 0; bn < 2; ++bn)
            #pragma unroll
            for (int j = 0; j < 4; ++j) {
                int row = brow + am * 16 + fj4 + j;
                int col = bcol + wc + bn * 16 + fr;
                D[(size_t)row * Nn + col] = f2bf(acc[am][bn][j] * scale);
            }
}

// Output projection + bias + residual, fp32 out
__global__ __launch_bounds__(256) void gemm_out_kernel(
    const u16* __restrict__ A, const u16* __restrict__ Bm,
    const float* __restrict__ bias, const float* __restrict__ resid,
    float* __restrict__ D, int M, int Nn, int K)
{
    __shared__ u16 As[64 * 32];
    __shared__ u16 Bs[128 * 32];
    const int brow = blockIdx.y * 64;
    const int bcol = blockIdx.x * 128;
    f32x4 acc[4][2];
    #pragma unroll
    for (int am = 0; am < 4; ++am)
        #pragma unroll
        for (int bn = 0; bn < 2; ++bn)
            acc[am][bn] = (f32x4){0.f, 0.f, 0.f, 0.f};

    gemm_core_64x128(A, Bm, K, brow, bcol, As, Bs, acc);

    const int lane = threadIdx.x & 63;
    const int wc = (threadIdx.x >> 6) * 32;
    const int fr = lane & 15;
    const int fj4 = (lane >> 4) * 4;
    #pragma unroll
    for (int am = 0; am < 4; ++am)
        #pragma unroll
        for (int bn = 0; bn < 2; ++bn)
            #pragma unroll
            for (int j = 0; j < 4; ++j) {
                int row = brow + am * 16 + fj4 + j;
                int col = bcol + wc + bn * 16 + fr;
                D[(size_t)row * Nn + col] = acc[am][bn][j] + bias[col] + resid[(size_t)row * Nn + col];
            }
}

// ---------------------------------------------------------------------------
// V transpose: V[b][n][h*64+d] -> Vt[bh][d][n]  (LDS-tiled, 64x64 tiles)
// ---------------------------------------------------------------------------
__global__ __launch_bounds__(256) void vtrans_kernel(
    const u16* __restrict__ V, u16* __restrict__ Vt)
{
    __shared__ u16 T[64][66];
    const int tid = threadIdx.x;
    const int bh  = blockIdx.y;
    const int kv0 = blockIdx.x * 64;
    const size_t rowbase = (size_t)(bh >> 4) * SEQ;
    const int colbase = (bh & 15) * DHEAD;

    {
        const int r = tid >> 2;
        const int c = (tid & 3) * 16;
        const u16* src = V + (rowbase + kv0 + r) * DMODEL + colbase + c;
        uint4 a = *(const uint4*)(src);
        uint4 b = *(const uint4*)(src + 8);
        uint32_t* dst = (uint32_t*)&T[r][c];
        dst[0] = a.x; dst[1] = a.y; dst[2] = a.z; dst[3] = a.w;
        dst[4] = b.x; dst[5] = b.y; dst[6] = b.z; dst[7] = b.w;
    }
    __syncthreads();
    {
        const int d = tid >> 2;
        const int c = (tid & 3) * 16;
        union { uint4 v; u16 e[8]; } o0, o1;
        #pragma unroll
        for (int j = 0; j < 8; ++j) o0.e[j] = T[c + j][d];
        #pragma unroll
        for (int j = 0; j < 8; ++j) o1.e[j] = T[c + 8 + j][d];
        u16* dst = Vt + (size_t)bh * DHEAD * SEQ + (size_t)d * SEQ + kv0 + c;
        *(uint4*)(dst) = o0.v;
        *(uint4*)(dst + 8) = o1.v;
    }
}

// ---------------------------------------------------------------------------
// Flash attention (r6 structure - measured best at ~73 us):
// deferred softmax + swapped QK^T; K and Vt double-buffered in LDS via
// global_load_lds, XOR-swizzled; q-tile 128, 4 waves x 32 q-rows, grid 512,
// bijective XCD swizzle.
// ---------------------------------------------------------------------------
__global__ __launch_bounds__(256, 3) void attn_kernel(
    const u16* __restrict__ Qb, const u16* __restrict__ Kb, const u16* __restrict__ Vt,
    u16* __restrict__ AO)
{
    __shared__ u16 Ks[2][64 * 64];   // [kv][d], chunk-swizzled
    __shared__ u16 Vs[2][64 * 64];   // [d][kv], chunk-swizzled
    __shared__ u16 Ps[128 * 72];

    const int tid  = threadIdx.x;
    const int lane = tid & 63;
    const int wave = tid >> 6;

    // bijective XCD swizzle: 512 blocks, 8 XCDs -> 64 blocks/XCD = 4 heads
    const int lin  = blockIdx.x;
    const int nlin = (lin & 7) * 64 + (lin >> 3);
    const int qblk = nlin & 15;          // 16 q-tiles of 128 rows
    const int bh   = nlin >> 4;          // 32 (b,h) pairs

    const size_t rowbase = (size_t)(bh >> 4) * SEQ;
    const int colbase = (bh & 15) * DHEAD;
    const int q0 = qblk * 128;
    const int fr  = lane & 15;
    const int g   = lane >> 4;
    const int fk  = g * 8;
    const int fj4 = g * 4;
    const int qw  = wave * 32;

    const u16* Kh = Kb + rowbase * DMODEL + colbase;   // rows: kv, stride DMODEL
    const u16* Vh = Vt + (size_t)bh * DHEAD * SEQ;     // rows: d,  stride SEQ

    // staging decomposition: linear LDS dest + inverse-swizzled global source
    const int sr  = tid >> 3;
    const int sc  = tid & 7;
    const int scs = (sc ^ (sr & 7)) << 3;   // source col, u16 units
    const int sdst = sr * 64 + sc * 8;      // linear LDS dest, u16 units

    // Q fragments hoisted (1/sqrt(dk)*log2e folded into Q projection)
    bf16x8 qf[2][2];
    #pragma unroll
    for (int am = 0; am < 2; ++am)
        #pragma unroll
        for (int kc = 0; kc < 2; ++kc)
            qf[am][kc] = *(const bf16x8*)(Qb + (rowbase + q0 + qw + am * 16 + fr) * DMODEL
                                             + colbase + kc * 32 + fk);

    f32x4 oacc[2][4];
    float lsum[2];
    #pragma unroll
    for (int am = 0; am < 2; ++am) {
        #pragma unroll
        for (int dn = 0; dn < 4; ++dn) oacc[am][dn] = (f32x4){0.f, 0.f, 0.f, 0.f};
        lsum[am] = 0.f;
    }

    // prologue: stage tile 0 into buffer 0
    gload_lds16(Kh + (size_t)(sr)      * DMODEL + scs, &Ks[0][sdst]);
    gload_lds16(Kh + (size_t)(32 + sr) * DMODEL + scs, &Ks[0][2048 + sdst]);
    gload_lds16(Vh + (size_t)(sr)      * SEQ    + scs, &Vs[0][sdst]);
    gload_lds16(Vh + (size_t)(32 + sr) * SEQ    + scs, &Vs[0][2048 + sdst]);
    __syncthreads();

    int buf = 0;
    for (int kv0 = 0; kv0 < SEQ; kv0 += 64) {
        const int kvn = kv0 + 64;
        if (kvn < SEQ) {   // prefetch next tile into buf^1 (overlaps compute)
            gload_lds16(Kh + (size_t)(kvn + sr)      * DMODEL + scs, &Ks[buf ^ 1][sdst]);
            gload_lds16(Kh + (size_t)(kvn + 32 + sr) * DMODEL + scs, &Ks[buf ^ 1][2048 + sdst]);
            gload_lds16(Vh + (size_t)(sr)      * SEQ + kvn + scs,    &Vs[buf ^ 1][sdst]);
            gload_lds16(Vh + (size_t)(32 + sr) * SEQ + kvn + scs,    &Vs[buf ^ 1][2048 + sdst]);
        }
        const u16* K0 = &Ks[buf][0];
        const u16* V0 = &Vs[buf][0];

        // S^T = K * Q^T (swapped): sacc[am][bn][j] = S[kv=bn*16+fj4+j][q=qw+am*16+fr]
        f32x4 sacc[2][4];
        #pragma unroll
        for (int am = 0; am < 2; ++am)
            #pragma unroll
            for (int bn = 0; bn < 4; ++bn)
                sacc[am][bn] = (f32x4){0.f, 0.f, 0.f, 0.f};
        __builtin_amdgcn_s_setprio(1);
        #pragma unroll
        for (int bn = 0; bn < 4; ++bn) {
            bf16x8 kf0 = *(const bf16x8*)(K0 + (bn * 16 + fr) * 64 + (((g)     ^ (fr & 7)) << 3));
            bf16x8 kf1 = *(const bf16x8*)(K0 + (bn * 16 + fr) * 64 + (((4 + g) ^ (fr & 7)) << 3));
            sacc[0][bn] = mfma16(kf0, qf[0][0], sacc[0][bn]);
            sacc[0][bn] = mfma16(kf1, qf[0][1], sacc[0][bn]);
            sacc[1][bn] = mfma16(kf0, qf[1][0], sacc[1][bn]);
            sacc[1][bn] = mfma16(kf1, qf[1][1], sacc[1][bn]);
        }
        __builtin_amdgcn_s_setprio(0);

        // deferred softmax: P = exp2(S'); lane-local l; packed bf16 + b64 store
        #pragma unroll
        for (int am = 0; am < 2; ++am) {
            float lacc = 0.f;
            #pragma unroll
            for (int bn = 0; bn < 4; ++bn) {
                float p0 = exp2f(sacc[am][bn][0]);
                float p1 = exp2f(sacc[am][bn][1]);
                float p2 = exp2f(sacc[am][bn][2]);
                float p3 = exp2f(sacc[am][bn][3]);
                uint2 w;
                w.x = pk2bf(p0, p1);
                w.y = pk2bf(p2, p3);
                *(uint2*)(Ps + (qw + am * 16 + fr) * 72 + bn * 16 + fj4) = w;
                lacc += (p0 + p1) + (p2 + p3);
            }
            lsum[am] += lacc;
        }

        // O += P * V  (Ps per-wave-private; lgkmcnt ordering only)
        bf16x8 pf[2][2];
        #pragma unroll
        for (int am = 0; am < 2; ++am)
            #pragma unroll
            for (int kc = 0; kc < 2; ++kc)
                pf[am][kc] = *(const bf16x8*)(Ps + (qw + am * 16 + fr) * 72 + kc * 32 + fk);
        __builtin_amdgcn_s_setprio(1);
        #pragma unroll
        for (int dn = 0; dn < 4; ++dn) {
            bf16x8 vf0 = *(const bf16x8*)(V0 + (dn * 16 + fr) * 64 + (((g)     ^ (fr & 7)) << 3));
            bf16x8 vf1 = *(const bf16x8*)(V0 + (dn * 16 + fr) * 64 + (((4 + g) ^ (fr & 7)) << 3));
            oacc[0][dn] = mfma16(pf[0][0], vf0, oacc[0][dn]);
            oacc[0][dn] = mfma16(pf[0][1], vf1, oacc[0][dn]);
            oacc[1][dn] = mfma16(pf[1][0], vf0, oacc[1][dn]);
            oacc[1][dn] = mfma16(pf[1][1], vf1, oacc[1][dn]);
        }
        __builtin_amdgcn_s_setprio(0);

        __syncthreads();   // drains prefetch vmcnt + protects buf swap
        buf ^= 1;
    }

    // final l reduction: sum across the 4 g-groups (same fr), then
    // redistribute per-output-row inverses (row = fj4 + j)
    float invj[2][4];
    #pragma unroll
    for (int am = 0; am < 2; ++am) {
        float l = lsum[am];
        l += __shfl_xor(l, 16);
        l += __shfl_xor(l, 32);
        #pragma unroll
        for (int j = 0; j < 4; ++j) {
            float lj = __shfl(l, (lane & 48) | (fj4 + j));
            invj[am][j] = 1.f / lj;
        }
    }

    // epilogue: O / l
    #pragma unroll
    for (int am = 0; am < 2; ++am)
        #pragma unroll
        for (int dn = 0; dn < 4; ++dn)
            #pragma unroll
            for (int j = 0; j < 4; ++j) {
                int row = q0 + qw + am * 16 + fj4 + j;
                AO[(rowbase + row) * DMODEL + colbase + dn * 16 + fr] =
                    f2bf(oacc[am][dn][j] * invj[am][j]);
            }
}

// ---------------------------------------------------------------------------
extern "C" void kernel_launch(void* const* d_in, const int* in_sizes, int n_in,
                              void* d_out, int out_size, void* d_ws, size_t ws_size,
                              hipStream_t stream)
{
    const float* q_f  = (const float*)d_in[0];
    const float* k_f  = (const float*)d_in[1];
    const float* v_f  = (const float*)d_in[2];
    const float* Wq_f = (const float*)d_in[3];
    const float* Wk_f = (const float*)d_in[4];
    const float* Wv_f = (const float*)d_in[5];
    const float* Wo_f = (const float*)d_in[6];
    const float* bo_f = (const float*)d_in[7];

    char* ws = (char*)d_ws;
    const size_t ACT = (size_t)BATCH * SEQ * DMODEL * sizeof(u16);   // 8 MB
    const size_t WSZ = (size_t)DMODEL * DMODEL * sizeof(u16);        // 2 MB
    u16* Xq  = (u16*)(ws);
    u16* Xk  = (u16*)(ws + ACT);
    u16* Xv  = (u16*)(ws + 2 * ACT);
    u16* Wqb = (u16*)(ws + 3 * ACT);
    u16* Wkb = (u16*)(ws + 3 * ACT + WSZ);
    u16* Wvb = (u16*)(ws + 3 * ACT + 2 * WSZ);
    u16* Wob = (u16*)(ws + 3 * ACT + 3 * WSZ);
    u16* Qb  = (u16*)(ws + 3 * ACT + 4 * WSZ);
    u16* Kb  = (u16*)(ws + 4 * ACT + 4 * WSZ);
    u16* Vb  = (u16*)(ws + 5 * ACT + 4 * WSZ);
    u16* AO  = (u16*)(ws + 6 * ACT + 4 * WSZ);   // total 7*ACT + 4*WSZ = 64 MB
    u16* Vt  = Xq;   // alias: Xq dead after gemm_qkv; cvt regenerates next call

    const int M = BATCH * SEQ;      // 4096
    const int Nn = DMODEL;          // 1024
    const int K = DMODEL;           // 1024

    cvt7_kernel<<<dim3(2048, 7, 1), 256, 0, stream>>>(
        q_f, k_f, v_f, Wq_f, Wk_f, Wv_f, Wo_f,
        Xq, Xk, Xv, Wqb, Wkb, Wvb, Wob);

    gemm_qkv_kernel<<<dim3(Nn / 128, M / 64, 3), 256, 0, stream>>>(
        Xq, Xk, Xv, Wqb, Wkb, Wvb, Qb, Kb, Vb, M, Nn, K);

    vtrans_kernel<<<dim3(SEQ / 64, BATCH * NHEAD, 1), 256, 0, stream>>>(Vb, Vt);

    attn_kernel<<<dim3(512, 1, 1), 256, 0, stream>>>(Qb, Kb, Vt, AO);

    gemm_out_kernel<<<dim3(Nn / 128, M / 64, 1), 256, 0, stream>>>(
        AO, Wob, bo_f, q_f, (float*)d_out, M, Nn, K);
}

// Round 12
// 154.977 us; speedup vs baseline: 1.1956x; 1.0283x over previous
//
#include <hip/hip_runtime.h>
#include <hip/hip_bf16.h>
#include <stdint.h>

#define BATCH  2
#define SEQ    2048
#define DMODEL 1024
#define NHEAD  16
#define DHEAD  64

typedef unsigned short u16;
typedef __attribute__((ext_vector_type(8))) short bf16x8;
typedef __attribute__((ext_vector_type(4))) float f32x4;

__device__ __forceinline__ u16 f2bf(float x) {
    union { float f; uint32_t u; } v; v.f = x;
    uint32_t r = v.u + 0x7fffu + ((v.u >> 16) & 1u);
    return (u16)(r >> 16);
}

__device__ __forceinline__ uint32_t pk2bf(float a, float b) {
    __hip_bfloat162 h = __float22bfloat162_rn(make_float2(a, b));
    return *(uint32_t*)&h;
}

__device__ __forceinline__ void gload_lds16(const void* g, void* l) {
    __builtin_amdgcn_global_load_lds(
        (const __attribute__((address_space(1))) uint32_t*)(uintptr_t)g,
        (__attribute__((address_space(3))) uint32_t*)(uintptr_t)l,
        16, 0, 0);
}

__device__ __forceinline__ f32x4 mfma16(bf16x8 a, bf16x8 b, f32x4 c) {
    return __builtin_amdgcn_mfma_f32_16x16x32_bf16(a, b, c, 0, 0, 0);
}

// ---------------------------------------------------------------------------
// f32 -> bf16 conversion for 3 activations + 4 weights (grid.y = segment)
// ---------------------------------------------------------------------------
__global__ __launch_bounds__(256) void cvt7_kernel(
    const float* s0, const float* s1, const float* s2, const float* s3,
    const float* s4, const float* s5, const float* s6,
    u16* d0, u16* d1, u16* d2, u16* d3, u16* d4, u16* d5, u16* d6)
{
    const float* s; u16* d; size_t n;
    switch (blockIdx.y) {
        case 0: s = s0; d = d0; n = (size_t)BATCH * SEQ * DMODEL; break;
        case 1: s = s1; d = d1; n = (size_t)BATCH * SEQ * DMODEL; break;
        case 2: s = s2; d = d2; n = (size_t)BATCH * SEQ * DMODEL; break;
        case 3: s = s3; d = d3; n = (size_t)DMODEL * DMODEL; break;
        case 4: s = s4; d = d4; n = (size_t)DMODEL * DMODEL; break;
        case 5: s = s5; d = d5; n = (size_t)DMODEL * DMODEL; break;
        default: s = s6; d = d6; n = (size_t)DMODEL * DMODEL; break;
    }
    size_t i = ((size_t)blockIdx.x * 256 + threadIdx.x) * 8;
    if (i >= n) return;
    float4 a = *(const float4*)(s + i);
    float4 b = *(const float4*)(s + i + 4);
    union { uint4 v; u16 e[8]; } u;
    u.e[0] = f2bf(a.x); u.e[1] = f2bf(a.y); u.e[2] = f2bf(a.z); u.e[3] = f2bf(a.w);
    u.e[4] = f2bf(b.x); u.e[5] = f2bf(b.y); u.e[6] = f2bf(b.z); u.e[7] = f2bf(b.w);
    *(uint4*)(d + i) = u.v;
}

// ---------------------------------------------------------------------------
// Shared 128x128 BT-GEMM core (m97 structure, r6-proven): C = A (MxK) * B^T
// ---------------------------------------------------------------------------
__device__ __forceinline__ void gemm_core_128(
    const u16* __restrict__ A, const u16* __restrict__ Bm, int K,
    int brow, int bcol, u16* As, u16* Bs, f32x4 (&acc)[4][4])
{
    const int tid  = threadIdx.x;
    const int lane = tid & 63;
    const int wr   = ((tid >> 6) >> 1) * 64;
    const int wc   = ((tid >> 6) & 1) * 64;
    const int srow = tid >> 2;
    const int scol = (tid & 3) * 8;
    const int fr   = lane & 15;
    const int fk   = (lane >> 4) * 8;

    for (int k0 = 0; k0 < K; k0 += 32) {
        gload_lds16(A  + (size_t)(brow + srow) * K + k0 + scol,       As + srow * 32 + scol);
        gload_lds16(A  + (size_t)(brow + 64 + srow) * K + k0 + scol,  As + (64 + srow) * 32 + scol);
        gload_lds16(Bm + (size_t)(bcol + srow) * K + k0 + scol,       Bs + srow * 32 + scol);
        gload_lds16(Bm + (size_t)(bcol + 64 + srow) * K + k0 + scol,  Bs + (64 + srow) * 32 + scol);
        __syncthreads();
        bf16x8 af[4], bfv[4];
        #pragma unroll
        for (int i = 0; i < 4; ++i) {
            af[i]  = *(const bf16x8*)(As + (wr + i * 16 + fr) * 32 + fk);
            bfv[i] = *(const bf16x8*)(Bs + (wc + i * 16 + fr) * 32 + fk);
        }
        #pragma unroll
        for (int am = 0; am < 4; ++am)
            #pragma unroll
            for (int bn = 0; bn < 4; ++bn)
                acc[am][bn] = mfma16(af[am], bfv[bn], acc[am][bn]);
        __syncthreads();
    }
}

// QKV projection: z selects (X, W, out).
// Q scale folds 1/sqrt(dk) AND log2(e) so attention can use exp2 directly.
__global__ __launch_bounds__(256) void gemm_qkv_kernel(
    const u16* __restrict__ Xq, const u16* __restrict__ Xk, const u16* __restrict__ Xv,
    const u16* __restrict__ Wq, const u16* __restrict__ Wk, const u16* __restrict__ Wv,
    u16* __restrict__ Qo, u16* __restrict__ Ko, u16* __restrict__ Vo,
    int M, int Nn, int K)
{
    __shared__ u16 As[128 * 32];
    __shared__ u16 Bs[128 * 32];
    const int z = blockIdx.z;
    const u16* A  = (z == 0) ? Xq : (z == 1) ? Xk : Xv;
    const u16* Bm = (z == 0) ? Wq : (z == 1) ? Wk : Wv;
    u16* D        = (z == 0) ? Qo : (z == 1) ? Ko : Vo;
    const float scale = (z == 0) ? 0.18033688011112042f : 1.0f;  // 0.125*log2(e)

    const int brow = blockIdx.y * 128;
    const int bcol = blockIdx.x * 128;
    f32x4 acc[4][4];
    #pragma unroll
    for (int am = 0; am < 4; ++am)
        #pragma unroll
        for (int bn = 0; bn < 4; ++bn)
            acc[am][bn] = (f32x4){0.f, 0.f, 0.f, 0.f};

    gemm_core_128(A, Bm, K, brow, bcol, As, Bs, acc);

    const int lane = threadIdx.x & 63;
    const int wr = ((threadIdx.x >> 6) >> 1) * 64;
    const int wc = ((threadIdx.x >> 6) & 1) * 64;
    const int fr = lane & 15;
    const int fj4 = (lane >> 4) * 4;
    #pragma unroll
    for (int am = 0; am < 4; ++am)
        #pragma unroll
        for (int bn = 0; bn < 4; ++bn)
            #pragma unroll
            for (int j = 0; j < 4; ++j) {
                int row = brow + wr + am * 16 + fj4 + j;
                int col = bcol + wc + bn * 16 + fr;
                D[(size_t)row * Nn + col] = f2bf(acc[am][bn][j] * scale);
            }
}

// Output projection + bias + residual, fp32 out
__global__ __launch_bounds__(256) void gemm_out_kernel(
    const u16* __restrict__ A, const u16* __restrict__ Bm,
    const float* __restrict__ bias, const float* __restrict__ resid,
    float* __restrict__ D, int M, int Nn, int K)
{
    __shared__ u16 As[128 * 32];
    __shared__ u16 Bs[128 * 32];
    const int brow = blockIdx.y * 128;
    const int bcol = blockIdx.x * 128;
    f32x4 acc[4][4];
    #pragma unroll
    for (int am = 0; am < 4; ++am)
        #pragma unroll
        for (int bn = 0; bn < 4; ++bn)
            acc[am][bn] = (f32x4){0.f, 0.f, 0.f, 0.f};

    gemm_core_128(A, Bm, K, brow, bcol, As, Bs, acc);

    const int lane = threadIdx.x & 63;
    const int wr = ((threadIdx.x >> 6) >> 1) * 64;
    const int wc = ((threadIdx.x >> 6) & 1) * 64;
    const int fr = lane & 15;
    const int fj4 = (lane >> 4) * 4;
    #pragma unroll
    for (int am = 0; am < 4; ++am)
        #pragma unroll
        for (int bn = 0; bn < 4; ++bn)
            #pragma unroll
            for (int j = 0; j < 4; ++j) {
                int row = brow + wr + am * 16 + fj4 + j;
                int col = bcol + wc + bn * 16 + fr;
                D[(size_t)row * Nn + col] = acc[am][bn][j] + bias[col] + resid[(size_t)row * Nn + col];
            }
}

// ---------------------------------------------------------------------------
// V transpose: V[b][n][h*64+d] -> Vt[bh][d][n]  (LDS-tiled, 64x64 tiles)
// ---------------------------------------------------------------------------
__global__ __launch_bounds__(256) void vtrans_kernel(
    const u16* __restrict__ V, u16* __restrict__ Vt)
{
    __shared__ u16 T[64][66];
    const int tid = threadIdx.x;
    const int bh  = blockIdx.y;
    const int kv0 = blockIdx.x * 64;
    const size_t rowbase = (size_t)(bh >> 4) * SEQ;
    const int colbase = (bh & 15) * DHEAD;

    {
        const int r = tid >> 2;
        const int c = (tid & 3) * 16;
        const u16* src = V + (rowbase + kv0 + r) * DMODEL + colbase + c;
        uint4 a = *(const uint4*)(src);
        uint4 b = *(const uint4*)(src + 8);
        uint32_t* dst = (uint32_t*)&T[r][c];
        dst[0] = a.x; dst[1] = a.y; dst[2] = a.z; dst[3] = a.w;
        dst[4] = b.x; dst[5] = b.y; dst[6] = b.z; dst[7] = b.w;
    }
    __syncthreads();
    {
        const int d = tid >> 2;
        const int c = (tid & 3) * 16;
        union { uint4 v; u16 e[8]; } o0, o1;
        #pragma unroll
        for (int j = 0; j < 8; ++j) o0.e[j] = T[c + j][d];
        #pragma unroll
        for (int j = 0; j < 8; ++j) o1.e[j] = T[c + 8 + j][d];
        u16* dst = Vt + (size_t)bh * DHEAD * SEQ + (size_t)d * SEQ + kv0 + c;
        *(uint4*)(dst) = o0.v;
        *(uint4*)(dst + 8) = o1.v;
    }
}

// ---------------------------------------------------------------------------
// Flash attention, 8-wave / q-tile 256 (m214-style geometry):
// one 512-thread block per CU (grid 256, XCD-swizzled: 4 complete heads/XCD).
// Per-CU K/V staging volume HALVED vs the 4-wave/128 structure: one block
// stages the 16KB K+V tile once per iter for 256 q-rows (512 threads cover
// the 512 16B chunks exactly once each). Per-wave compute identical to r6:
// deferred softmax + swapped QK^T, XOR-swizzled LDS, double-buffered.
// ---------------------------------------------------------------------------
__global__ __launch_bounds__(512, 1) void attn_kernel(
    const u16* __restrict__ Qb, const u16* __restrict__ Kb, const u16* __restrict__ Vt,
    u16* __restrict__ AO)
{
    __shared__ u16 Ks[2][64 * 64];   // [kv][d], chunk-swizzled (8 KB each)
    __shared__ u16 Vs[2][64 * 64];   // [d][kv], chunk-swizzled
    __shared__ u16 Ps[256 * 72];     // 36 KB

    const int tid  = threadIdx.x;
    const int lane = tid & 63;
    const int wave = tid >> 6;       // 0..7

    // bijective XCD swizzle: 256 blocks, 8 XCDs -> 32 blocks/XCD = 4 heads
    const int lin  = blockIdx.x;
    const int nlin = (lin & 7) * 32 + (lin >> 3);
    const int qblk = nlin & 7;           // 8 q-tiles of 256 rows
    const int bh   = nlin >> 3;          // 32 (b,h) pairs

    const size_t rowbase = (size_t)(bh >> 4) * SEQ;
    const int colbase = (bh & 15) * DHEAD;
    const int q0 = qblk * 256;
    const int fr  = lane & 15;
    const int g   = lane >> 4;
    const int fk  = g * 8;
    const int fj4 = g * 4;
    const int qw  = wave * 32;

    const u16* Kh = Kb + rowbase * DMODEL + colbase;   // rows: kv, stride DMODEL
    const u16* Vh = Vt + (size_t)bh * DHEAD * SEQ;     // rows: d,  stride SEQ

    // staging: 512 threads cover 64 rows x 8 chunks exactly once.
    // linear LDS dest + inverse-swizzled global source (rule #21)
    const int sr  = tid >> 3;               // 0..63
    const int sc  = tid & 7;
    const int scs = (sc ^ (sr & 7)) << 3;   // source col, u16 units
    const int sdst = sr * 64 + sc * 8;      // linear LDS dest, u16 units

    // Q fragments hoisted (1/sqrt(dk)*log2e folded into Q projection)
    bf16x8 qf[2][2];
    #pragma unroll
    for (int am = 0; am < 2; ++am)
        #pragma unroll
        for (int kc = 0; kc < 2; ++kc)
            qf[am][kc] = *(const bf16x8*)(Qb + (rowbase + q0 + qw + am * 16 + fr) * DMODEL
                                             + colbase + kc * 32 + fk);

    f32x4 oacc[2][4];
    float lsum[2];
    #pragma unroll
    for (int am = 0; am < 2; ++am) {
        #pragma unroll
        for (int dn = 0; dn < 4; ++dn) oacc[am][dn] = (f32x4){0.f, 0.f, 0.f, 0.f};
        lsum[am] = 0.f;
    }

    // prologue: stage tile 0 into buffer 0 (one K-chunk + one V-chunk per thread)
    gload_lds16(Kh + (size_t)sr * DMODEL + scs, &Ks[0][sdst]);
    gload_lds16(Vh + (size_t)sr * SEQ    + scs, &Vs[0][sdst]);
    __syncthreads();

    int buf = 0;
    for (int kv0 = 0; kv0 < SEQ; kv0 += 64) {
        const int kvn = kv0 + 64;
        if (kvn < SEQ) {   // prefetch next tile into buf^1 (overlaps compute)
            gload_lds16(Kh + (size_t)(kvn + sr) * DMODEL + scs, &Ks[buf ^ 1][sdst]);
            gload_lds16(Vh + (size_t)sr * SEQ + kvn + scs,      &Vs[buf ^ 1][sdst]);
        }
        const u16* K0 = &Ks[buf][0];
        const u16* V0 = &Vs[buf][0];

        // S^T = K * Q^T (swapped): sacc[am][bn][j] = S[kv=bn*16+fj4+j][q=qw+am*16+fr]
        f32x4 sacc[2][4];
        #pragma unroll
        for (int am = 0; am < 2; ++am)
            #pragma unroll
            for (int bn = 0; bn < 4; ++bn)
                sacc[am][bn] = (f32x4){0.f, 0.f, 0.f, 0.f};
        __builtin_amdgcn_s_setprio(1);
        #pragma unroll
        for (int bn = 0; bn < 4; ++bn) {
            bf16x8 kf0 = *(const bf16x8*)(K0 + (bn * 16 + fr) * 64 + (((g)     ^ (fr & 7)) << 3));
            bf16x8 kf1 = *(const bf16x8*)(K0 + (bn * 16 + fr) * 64 + (((4 + g) ^ (fr & 7)) << 3));
            sacc[0][bn] = mfma16(kf0, qf[0][0], sacc[0][bn]);
            sacc[0][bn] = mfma16(kf1, qf[0][1], sacc[0][bn]);
            sacc[1][bn] = mfma16(kf0, qf[1][0], sacc[1][bn]);
            sacc[1][bn] = mfma16(kf1, qf[1][1], sacc[1][bn]);
        }
        __builtin_amdgcn_s_setprio(0);

        // deferred softmax: P = exp2(S'); lane-local l; packed bf16 + b64 store
        #pragma unroll
        for (int am = 0; am < 2; ++am) {
            float lacc = 0.f;
            #pragma unroll
            for (int bn = 0; bn < 4; ++bn) {
                float p0 = exp2f(sacc[am][bn][0]);
                float p1 = exp2f(sacc[am][bn][1]);
                float p2 = exp2f(sacc[am][bn][2]);
                float p3 = exp2f(sacc[am][bn][3]);
                uint2 w;
                w.x = pk2bf(p0, p1);
                w.y = pk2bf(p2, p3);
                *(uint2*)(Ps + (qw + am * 16 + fr) * 72 + bn * 16 + fj4) = w;
                lacc += (p0 + p1) + (p2 + p3);
            }
            lsum[am] += lacc;
        }

        // O += P * V  (Ps per-wave-private; lgkmcnt ordering only)
        bf16x8 pf[2][2];
        #pragma unroll
        for (int am = 0; am < 2; ++am)
            #pragma unroll
            for (int kc = 0; kc < 2; ++kc)
                pf[am][kc] = *(const bf16x8*)(Ps + (qw + am * 16 + fr) * 72 + kc * 32 + fk);
        __builtin_amdgcn_s_setprio(1);
        #pragma unroll
        for (int dn = 0; dn < 4; ++dn) {
            bf16x8 vf0 = *(const bf16x8*)(V0 + (dn * 16 + fr) * 64 + (((g)     ^ (fr & 7)) << 3));
            bf16x8 vf1 = *(const bf16x8*)(V0 + (dn * 16 + fr) * 64 + (((4 + g) ^ (fr & 7)) << 3));
            oacc[0][dn] = mfma16(pf[0][0], vf0, oacc[0][dn]);
            oacc[0][dn] = mfma16(pf[0][1], vf1, oacc[0][dn]);
            oacc[1][dn] = mfma16(pf[1][0], vf0, oacc[1][dn]);
            oacc[1][dn] = mfma16(pf[1][1], vf1, oacc[1][dn]);
        }
        __builtin_amdgcn_s_setprio(0);

        __syncthreads();   // drains prefetch vmcnt + protects buf swap
        buf ^= 1;
    }

    // final l reduction: sum across the 4 g-groups (same fr), then
    // redistribute per-output-row inverses (row = fj4 + j)
    float invj[2][4];
    #pragma unroll
    for (int am = 0; am < 2; ++am) {
        float l = lsum[am];
        l += __shfl_xor(l, 16);
        l += __shfl_xor(l, 32);
        #pragma unroll
        for (int j = 0; j < 4; ++j) {
            float lj = __shfl(l, (lane & 48) | (fj4 + j));
            invj[am][j] = 1.f / lj;
        }
    }

    // epilogue: O / l
    #pragma unroll
    for (int am = 0; am < 2; ++am)
        #pragma unroll
        for (int dn = 0; dn < 4; ++dn)
            #pragma unroll
            for (int j = 0; j < 4; ++j) {
                int row = q0 + qw + am * 16 + fj4 + j;
                AO[(rowbase + row) * DMODEL + colbase + dn * 16 + fr] =
                    f2bf(oacc[am][dn][j] * invj[am][j]);
            }
}

// ---------------------------------------------------------------------------
extern "C" void kernel_launch(void* const* d_in, const int* in_sizes, int n_in,
                              void* d_out, int out_size, void* d_ws, size_t ws_size,
                              hipStream_t stream)
{
    const float* q_f  = (const float*)d_in[0];
    const float* k_f  = (const float*)d_in[1];
    const float* v_f  = (const float*)d_in[2];
    const float* Wq_f = (const float*)d_in[3];
    const float* Wk_f = (const float*)d_in[4];
    const float* Wv_f = (const float*)d_in[5];
    const float* Wo_f = (const float*)d_in[6];
    const float* bo_f = (const float*)d_in[7];

    char* ws = (char*)d_ws;
    const size_t ACT = (size_t)BATCH * SEQ * DMODEL * sizeof(u16);   // 8 MB
    const size_t WSZ = (size_t)DMODEL * DMODEL * sizeof(u16);        // 2 MB
    u16* Xq  = (u16*)(ws);
    u16* Xk  = (u16*)(ws + ACT);
    u16* Xv  = (u16*)(ws + 2 * ACT);
    u16* Wqb = (u16*)(ws + 3 * ACT);
    u16* Wkb = (u16*)(ws + 3 * ACT + WSZ);
    u16* Wvb = (u16*)(ws + 3 * ACT + 2 * WSZ);
    u16* Wob = (u16*)(ws + 3 * ACT + 3 * WSZ);
    u16* Qb  = (u16*)(ws + 3 * ACT + 4 * WSZ);
    u16* Kb  = (u16*)(ws + 4 * ACT + 4 * WSZ);
    u16* Vb  = (u16*)(ws + 5 * ACT + 4 * WSZ);
    u16* AO  = (u16*)(ws + 6 * ACT + 4 * WSZ);   // total 7*ACT + 4*WSZ = 64 MB
    u16* Vt  = Xq;   // alias: Xq dead after gemm_qkv; cvt regenerates next call

    const int M = BATCH * SEQ;      // 4096
    const int Nn = DMODEL;          // 1024
    const int K = DMODEL;           // 1024

    cvt7_kernel<<<dim3(2048, 7, 1), 256, 0, stream>>>(
        q_f, k_f, v_f, Wq_f, Wk_f, Wv_f, Wo_f,
        Xq, Xk, Xv, Wqb, Wkb, Wvb, Wob);

    gemm_qkv_kernel<<<dim3(Nn / 128, M / 128, 3), 256, 0, stream>>>(
        Xq, Xk, Xv, Wqb, Wkb, Wvb, Qb, Kb, Vb, M, Nn, K);

    vtrans_kernel<<<dim3(SEQ / 64, BATCH * NHEAD, 1), 256, 0, stream>>>(Vb, Vt);

    attn_kernel<<<dim3(256, 1, 1), 512, 0, stream>>>(Qb, Kb, Vt, AO);

    gemm_out_kernel<<<dim3(Nn / 128, M / 128, 1), 256, 0, stream>>>(
        AO, Wob, bo_f, q_f, (float*)d_out, M, Nn, K);
}

// Round 13
// 142.316 us; speedup vs baseline: 1.3019x; 1.0890x over previous
//
#include <hip/hip_runtime.h>
#include <hip/hip_bf16.h>
#include <stdint.h>

#define BATCH  2
#define SEQ    2048
#define DMODEL 1024
#define NHEAD  16
#define DHEAD  64

typedef unsigned short u16;
typedef __attribute__((ext_vector_type(8))) short bf16x8;
typedef __attribute__((ext_vector_type(4))) float f32x4;

__device__ __forceinline__ u16 f2bf(float x) {
    union { float f; uint32_t u; } v; v.f = x;
    uint32_t r = v.u + 0x7fffu + ((v.u >> 16) & 1u);
    return (u16)(r >> 16);
}

__device__ __forceinline__ uint32_t pk2bf(float a, float b) {
    __hip_bfloat162 h = __float22bfloat162_rn(make_float2(a, b));
    return *(uint32_t*)&h;
}

__device__ __forceinline__ void gload_lds16(const void* g, void* l) {
    __builtin_amdgcn_global_load_lds(
        (const __attribute__((address_space(1))) uint32_t*)(uintptr_t)g,
        (__attribute__((address_space(3))) uint32_t*)(uintptr_t)l,
        16, 0, 0);
}

__device__ __forceinline__ f32x4 mfma16(bf16x8 a, bf16x8 b, f32x4 c) {
    return __builtin_amdgcn_mfma_f32_16x16x32_bf16(a, b, c, 0, 0, 0);
}

// ---------------------------------------------------------------------------
// f32 -> bf16 conversion for 3 activations + 4 weights (grid.y = segment)
// ---------------------------------------------------------------------------
__global__ __launch_bounds__(256) void cvt7_kernel(
    const float* s0, const float* s1, const float* s2, const float* s3,
    const float* s4, const float* s5, const float* s6,
    u16* d0, u16* d1, u16* d2, u16* d3, u16* d4, u16* d5, u16* d6)
{
    const float* s; u16* d; size_t n;
    switch (blockIdx.y) {
        case 0: s = s0; d = d0; n = (size_t)BATCH * SEQ * DMODEL; break;
        case 1: s = s1; d = d1; n = (size_t)BATCH * SEQ * DMODEL; break;
        case 2: s = s2; d = d2; n = (size_t)BATCH * SEQ * DMODEL; break;
        case 3: s = s3; d = d3; n = (size_t)DMODEL * DMODEL; break;
        case 4: s = s4; d = d4; n = (size_t)DMODEL * DMODEL; break;
        case 5: s = s5; d = d5; n = (size_t)DMODEL * DMODEL; break;
        default: s = s6; d = d6; n = (size_t)DMODEL * DMODEL; break;
    }
    size_t i = ((size_t)blockIdx.x * 256 + threadIdx.x) * 8;
    if (i >= n) return;
    float4 a = *(const float4*)(s + i);
    float4 b = *(const float4*)(s + i + 4);
    union { uint4 v; u16 e[8]; } u;
    u.e[0] = f2bf(a.x); u.e[1] = f2bf(a.y); u.e[2] = f2bf(a.z); u.e[3] = f2bf(a.w);
    u.e[4] = f2bf(b.x); u.e[5] = f2bf(b.y); u.e[6] = f2bf(b.z); u.e[7] = f2bf(b.w);
    *(uint4*)(d + i) = u.v;
}

// ---------------------------------------------------------------------------
// Shared 128x128 BT-GEMM core (m97 structure, r6-proven): C = A (MxK) * B^T
// ---------------------------------------------------------------------------
__device__ __forceinline__ void gemm_core_128(
    const u16* __restrict__ A, const u16* __restrict__ Bm, int K,
    int brow, int bcol, u16* As, u16* Bs, f32x4 (&acc)[4][4])
{
    const int tid  = threadIdx.x;
    const int lane = tid & 63;
    const int wr   = ((tid >> 6) >> 1) * 64;
    const int wc   = ((tid >> 6) & 1) * 64;
    const int srow = tid >> 2;
    const int scol = (tid & 3) * 8;
    const int fr   = lane & 15;
    const int fk   = (lane >> 4) * 8;

    for (int k0 = 0; k0 < K; k0 += 32) {
        gload_lds16(A  + (size_t)(brow + srow) * K + k0 + scol,       As + srow * 32 + scol);
        gload_lds16(A  + (size_t)(brow + 64 + srow) * K + k0 + scol,  As + (64 + srow) * 32 + scol);
        gload_lds16(Bm + (size_t)(bcol + srow) * K + k0 + scol,       Bs + srow * 32 + scol);
        gload_lds16(Bm + (size_t)(bcol + 64 + srow) * K + k0 + scol,  Bs + (64 + srow) * 32 + scol);
        __syncthreads();
        bf16x8 af[4], bfv[4];
        #pragma unroll
        for (int i = 0; i < 4; ++i) {
            af[i]  = *(const bf16x8*)(As + (wr + i * 16 + fr) * 32 + fk);
            bfv[i] = *(const bf16x8*)(Bs + (wc + i * 16 + fr) * 32 + fk);
        }
        #pragma unroll
        for (int am = 0; am < 4; ++am)
            #pragma unroll
            for (int bn = 0; bn < 4; ++bn)
                acc[am][bn] = mfma16(af[am], bfv[bn], acc[am][bn]);
        __syncthreads();
    }
}

// ---------------------------------------------------------------------------
// 64x128 BT-GEMM core: for the 1-block/CU out-projection shape only.
// ---------------------------------------------------------------------------
__device__ __forceinline__ void gemm_core_64x128(
    const u16* __restrict__ A, const u16* __restrict__ Bm, int K,
    int brow, int bcol, u16* As, u16* Bs, f32x4 (&acc)[4][2])
{
    const int tid  = threadIdx.x;
    const int lane = tid & 63;
    const int wc   = (tid >> 6) * 32;
    const int srow = tid >> 2;
    const int scol = (tid & 3) * 8;
    const int fr   = lane & 15;
    const int fk   = (lane >> 4) * 8;

    for (int k0 = 0; k0 < K; k0 += 32) {
        gload_lds16(A  + (size_t)(brow + srow) * K + k0 + scol,       As + srow * 32 + scol);
        gload_lds16(Bm + (size_t)(bcol + srow) * K + k0 + scol,       Bs + srow * 32 + scol);
        gload_lds16(Bm + (size_t)(bcol + 64 + srow) * K + k0 + scol,  Bs + (64 + srow) * 32 + scol);
        __syncthreads();
        bf16x8 af[4], bfv[2];
        #pragma unroll
        for (int i = 0; i < 4; ++i)
            af[i]  = *(const bf16x8*)(As + (i * 16 + fr) * 32 + fk);
        #pragma unroll
        for (int i = 0; i < 2; ++i)
            bfv[i] = *(const bf16x8*)(Bs + (wc + i * 16 + fr) * 32 + fk);
        #pragma unroll
        for (int am = 0; am < 4; ++am)
            #pragma unroll
            for (int bn = 0; bn < 2; ++bn)
                acc[am][bn] = mfma16(af[am], bfv[bn], acc[am][bn]);
        __syncthreads();
    }
}

// QKV projection: z selects (X, W, out); XCD-swizzled block mapping.
// Q scale folds 1/sqrt(dk) AND log2(e) so attention can use exp2 directly.
__global__ __launch_bounds__(256) void gemm_qkv_kernel(
    const u16* __restrict__ Xq, const u16* __restrict__ Xk, const u16* __restrict__ Xv,
    const u16* __restrict__ Wq, const u16* __restrict__ Wk, const u16* __restrict__ Wv,
    u16* __restrict__ Qo, u16* __restrict__ Ko, u16* __restrict__ Vo,
    int M, int Nn, int K)
{
    __shared__ u16 As[128 * 32];
    __shared__ u16 Bs[128 * 32];
    const int z = blockIdx.z;
    const u16* A  = (z == 0) ? Xq : (z == 1) ? Xk : Xv;
    const u16* Bm = (z == 0) ? Wq : (z == 1) ? Wk : Wv;
    u16* D        = (z == 0) ? Qo : (z == 1) ? Ko : Vo;
    const float scale = (z == 0) ? 0.18033688011112042f : 1.0f;  // 0.125*log2(e)

    // bijective XCD swizzle: 256 blocks/z, 8 XCDs -> 32 consecutive blocks/XCD
    // (each XCD's L2 holds 8 A-panels + 4 B-panels ~ 3 MB)
    const int lin  = blockIdx.y * gridDim.x + blockIdx.x;
    const int nlin = (lin & 7) * 32 + (lin >> 3);
    const int brow = (nlin >> 3) * 128;
    const int bcol = (nlin & 7) * 128;
    f32x4 acc[4][4];
    #pragma unroll
    for (int am = 0; am < 4; ++am)
        #pragma unroll
        for (int bn = 0; bn < 4; ++bn)
            acc[am][bn] = (f32x4){0.f, 0.f, 0.f, 0.f};

    gemm_core_128(A, Bm, K, brow, bcol, As, Bs, acc);

    const int lane = threadIdx.x & 63;
    const int wr = ((threadIdx.x >> 6) >> 1) * 64;
    const int wc = ((threadIdx.x >> 6) & 1) * 64;
    const int fr = lane & 15;
    const int fj4 = (lane >> 4) * 4;
    #pragma unroll
    for (int am = 0; am < 4; ++am)
        #pragma unroll
        for (int bn = 0; bn < 4; ++bn)
            #pragma unroll
            for (int j = 0; j < 4; ++j) {
                int row = brow + wr + am * 16 + fj4 + j;
                int col = bcol + wc + bn * 16 + fr;
                D[(size_t)row * Nn + col] = f2bf(acc[am][bn][j] * scale);
            }
}

// Output projection + bias + residual, fp32 out. 64x128 tiles (512 blocks =
// 2 blocks/CU; this GEMM was the pipeline's only 1-block/CU dispatch).
__global__ __launch_bounds__(256, 2) void gemm_out_kernel(
    const u16* __restrict__ A, const u16* __restrict__ Bm,
    const float* __restrict__ bias, const float* __restrict__ resid,
    float* __restrict__ D, int M, int Nn, int K)
{
    __shared__ u16 As[64 * 32];
    __shared__ u16 Bs[128 * 32];

    // bijective XCD swizzle: 512 blocks, 8 XCDs -> 64 consecutive blocks/XCD
    const int lin  = blockIdx.y * gridDim.x + blockIdx.x;
    const int nlin = (lin & 7) * 64 + (lin >> 3);
    const int brow = (nlin >> 3) * 64;
    const int bcol = (nlin & 7) * 128;
    f32x4 acc[4][2];
    #pragma unroll
    for (int am = 0; am < 4; ++am)
        #pragma unroll
        for (int bn = 0; bn < 2; ++bn)
            acc[am][bn] = (f32x4){0.f, 0.f, 0.f, 0.f};

    gemm_core_64x128(A, Bm, K, brow, bcol, As, Bs, acc);

    const int lane = threadIdx.x & 63;
    const int wc = (threadIdx.x >> 6) * 32;
    const int fr = lane & 15;
    const int fj4 = (lane >> 4) * 4;
    #pragma unroll
    for (int am = 0; am < 4; ++am)
        #pragma unroll
        for (int bn = 0; bn < 2; ++bn)
            #pragma unroll
            for (int j = 0; j < 4; ++j) {
                int row = brow + am * 16 + fj4 + j;
                int col = bcol + wc + bn * 16 + fr;
                D[(size_t)row * Nn + col] = acc[am][bn][j] + bias[col] + resid[(size_t)row * Nn + col];
            }
}

// ---------------------------------------------------------------------------
// V transpose: V[b][n][h*64+d] -> Vt[bh][d][n]  (LDS-tiled, 64x64 tiles)
// ---------------------------------------------------------------------------
__global__ __launch_bounds__(256) void vtrans_kernel(
    const u16* __restrict__ V, u16* __restrict__ Vt)
{
    __shared__ u16 T[64][66];
    const int tid = threadIdx.x;
    const int bh  = blockIdx.y;
    const int kv0 = blockIdx.x * 64;
    const size_t rowbase = (size_t)(bh >> 4) * SEQ;
    const int colbase = (bh & 15) * DHEAD;

    {
        const int r = tid >> 2;
        const int c = (tid & 3) * 16;
        const u16* src = V + (rowbase + kv0 + r) * DMODEL + colbase + c;
        uint4 a = *(const uint4*)(src);
        uint4 b = *(const uint4*)(src + 8);
        uint32_t* dst = (uint32_t*)&T[r][c];
        dst[0] = a.x; dst[1] = a.y; dst[2] = a.z; dst[3] = a.w;
        dst[4] = b.x; dst[5] = b.y; dst[6] = b.z; dst[7] = b.w;
    }
    __syncthreads();
    {
        const int d = tid >> 2;
        const int c = (tid & 3) * 16;
        union { uint4 v; u16 e[8]; } o0, o1;
        #pragma unroll
        for (int j = 0; j < 8; ++j) o0.e[j] = T[c + j][d];
        #pragma unroll
        for (int j = 0; j < 8; ++j) o1.e[j] = T[c + 8 + j][d];
        u16* dst = Vt + (size_t)bh * DHEAD * SEQ + (size_t)d * SEQ + kv0 + c;
        *(uint4*)(dst) = o0.v;
        *(uint4*)(dst + 8) = o1.v;
    }
}

// ---------------------------------------------------------------------------
// Flash attention, 8-wave / q-tile 256 (r12, measured 71.6 us):
// one 512-thread block per CU (grid 256, XCD-swizzled). Deferred softmax +
// swapped QK^T, XOR-swizzled LDS, double-buffered K/V via global_load_lds.
// ---------------------------------------------------------------------------
__global__ __launch_bounds__(512, 1) void attn_kernel(
    const u16* __restrict__ Qb, const u16* __restrict__ Kb, const u16* __restrict__ Vt,
    u16* __restrict__ AO)
{
    __shared__ u16 Ks[2][64 * 64];   // [kv][d], chunk-swizzled (8 KB each)
    __shared__ u16 Vs[2][64 * 64];   // [d][kv], chunk-swizzled
    __shared__ u16 Ps[256 * 72];     // 36 KB

    const int tid  = threadIdx.x;
    const int lane = tid & 63;
    const int wave = tid >> 6;       // 0..7

    // bijective XCD swizzle: 256 blocks, 8 XCDs -> 32 blocks/XCD = 4 heads
    const int lin  = blockIdx.x;
    const int nlin = (lin & 7) * 32 + (lin >> 3);
    const int qblk = nlin & 7;           // 8 q-tiles of 256 rows
    const int bh   = nlin >> 3;          // 32 (b,h) pairs

    const size_t rowbase = (size_t)(bh >> 4) * SEQ;
    const int colbase = (bh & 15) * DHEAD;
    const int q0 = qblk * 256;
    const int fr  = lane & 15;
    const int g   = lane >> 4;
    const int fk  = g * 8;
    const int fj4 = g * 4;
    const int qw  = wave * 32;

    const u16* Kh = Kb + rowbase * DMODEL + colbase;   // rows: kv, stride DMODEL
    const u16* Vh = Vt + (size_t)bh * DHEAD * SEQ;     // rows: d,  stride SEQ

    // staging: 512 threads cover 64 rows x 8 chunks exactly once.
    // linear LDS dest + inverse-swizzled global source (rule #21)
    const int sr  = tid >> 3;               // 0..63
    const int sc  = tid & 7;
    const int scs = (sc ^ (sr & 7)) << 3;   // source col, u16 units
    const int sdst = sr * 64 + sc * 8;      // linear LDS dest, u16 units

    // Q fragments hoisted (1/sqrt(dk)*log2e folded into Q projection)
    bf16x8 qf[2][2];
    #pragma unroll
    for (int am = 0; am < 2; ++am)
        #pragma unroll
        for (int kc = 0; kc < 2; ++kc)
            qf[am][kc] = *(const bf16x8*)(Qb + (rowbase + q0 + qw + am * 16 + fr) * DMODEL
                                             + colbase + kc * 32 + fk);

    f32x4 oacc[2][4];
    float lsum[2];
    #pragma unroll
    for (int am = 0; am < 2; ++am) {
        #pragma unroll
        for (int dn = 0; dn < 4; ++dn) oacc[am][dn] = (f32x4){0.f, 0.f, 0.f, 0.f};
        lsum[am] = 0.f;
    }

    // prologue: stage tile 0 into buffer 0 (one K-chunk + one V-chunk per thread)
    gload_lds16(Kh + (size_t)sr * DMODEL + scs, &Ks[0][sdst]);
    gload_lds16(Vh + (size_t)sr * SEQ    + scs, &Vs[0][sdst]);
    __syncthreads();

    int buf = 0;
    for (int kv0 = 0; kv0 < SEQ; kv0 += 64) {
        const int kvn = kv0 + 64;
        if (kvn < SEQ) {   // prefetch next tile into buf^1 (overlaps compute)
            gload_lds16(Kh + (size_t)(kvn + sr) * DMODEL + scs, &Ks[buf ^ 1][sdst]);
            gload_lds16(Vh + (size_t)sr * SEQ + kvn + scs,      &Vs[buf ^ 1][sdst]);
        }
        const u16* K0 = &Ks[buf][0];
        const u16* V0 = &Vs[buf][0];

        // S^T = K * Q^T (swapped): sacc[am][bn][j] = S[kv=bn*16+fj4+j][q=qw+am*16+fr]
        f32x4 sacc[2][4];
        #pragma unroll
        for (int am = 0; am < 2; ++am)
            #pragma unroll
            for (int bn = 0; bn < 4; ++bn)
                sacc[am][bn] = (f32x4){0.f, 0.f, 0.f, 0.f};
        __builtin_amdgcn_s_setprio(1);
        #pragma unroll
        for (int bn = 0; bn < 4; ++bn) {
            bf16x8 kf0 = *(const bf16x8*)(K0 + (bn * 16 + fr) * 64 + (((g)     ^ (fr & 7)) << 3));
            bf16x8 kf1 = *(const bf16x8*)(K0 + (bn * 16 + fr) * 64 + (((4 + g) ^ (fr & 7)) << 3));
            sacc[0][bn] = mfma16(kf0, qf[0][0], sacc[0][bn]);
            sacc[0][bn] = mfma16(kf1, qf[0][1], sacc[0][bn]);
            sacc[1][bn] = mfma16(kf0, qf[1][0], sacc[1][bn]);
            sacc[1][bn] = mfma16(kf1, qf[1][1], sacc[1][bn]);
        }
        __builtin_amdgcn_s_setprio(0);

        // deferred softmax: P = exp2(S'); lane-local l; packed bf16 + b64 store
        #pragma unroll
        for (int am = 0; am < 2; ++am) {
            float lacc = 0.f;
            #pragma unroll
            for (int bn = 0; bn < 4; ++bn) {
                float p0 = exp2f(sacc[am][bn][0]);
                float p1 = exp2f(sacc[am][bn][1]);
                float p2 = exp2f(sacc[am][bn][2]);
                float p3 = exp2f(sacc[am][bn][3]);
                uint2 w;
                w.x = pk2bf(p0, p1);
                w.y = pk2bf(p2, p3);
                *(uint2*)(Ps + (qw + am * 16 + fr) * 72 + bn * 16 + fj4) = w;
                lacc += (p0 + p1) + (p2 + p3);
            }
            lsum[am] += lacc;
        }

        // O += P * V  (Ps per-wave-private; lgkmcnt ordering only)
        bf16x8 pf[2][2];
        #pragma unroll
        for (int am = 0; am < 2; ++am)
            #pragma unroll
            for (int kc = 0; kc < 2; ++kc)
                pf[am][kc] = *(const bf16x8*)(Ps + (qw + am * 16 + fr) * 72 + kc * 32 + fk);
        __builtin_amdgcn_s_setprio(1);
        #pragma unroll
        for (int dn = 0; dn < 4; ++dn) {
            bf16x8 vf0 = *(const bf16x8*)(V0 + (dn * 16 + fr) * 64 + (((g)     ^ (fr & 7)) << 3));
            bf16x8 vf1 = *(const bf16x8*)(V0 + (dn * 16 + fr) * 64 + (((4 + g) ^ (fr & 7)) << 3));
            oacc[0][dn] = mfma16(pf[0][0], vf0, oacc[0][dn]);
            oacc[0][dn] = mfma16(pf[0][1], vf1, oacc[0][dn]);
            oacc[1][dn] = mfma16(pf[1][0], vf0, oacc[1][dn]);
            oacc[1][dn] = mfma16(pf[1][1], vf1, oacc[1][dn]);
        }
        __builtin_amdgcn_s_setprio(0);

        __syncthreads();   // drains prefetch vmcnt + protects buf swap
        buf ^= 1;
    }

    // final l reduction: sum across the 4 g-groups (same fr), then
    // redistribute per-output-row inverses (row = fj4 + j)
    float invj[2][4];
    #pragma unroll
    for (int am = 0; am < 2; ++am) {
        float l = lsum[am];
        l += __shfl_xor(l, 16);
        l += __shfl_xor(l, 32);
        #pragma unroll
        for (int j = 0; j < 4; ++j) {
            float lj = __shfl(l, (lane & 48) | (fj4 + j));
            invj[am][j] = 1.f / lj;
        }
    }

    // epilogue: O / l
    #pragma unroll
    for (int am = 0; am < 2; ++am)
        #pragma unroll
        for (int dn = 0; dn < 4; ++dn)
            #pragma unroll
            for (int j = 0; j < 4; ++j) {
                int row = q0 + qw + am * 16 + fj4 + j;
                AO[(rowbase + row) * DMODEL + colbase + dn * 16 + fr] =
                    f2bf(oacc[am][dn][j] * invj[am][j]);
            }
}

// ---------------------------------------------------------------------------
extern "C" void kernel_launch(void* const* d_in, const int* in_sizes, int n_in,
                              void* d_out, int out_size, void* d_ws, size_t ws_size,
                              hipStream_t stream)
{
    const float* q_f  = (const float*)d_in[0];
    const float* k_f  = (const float*)d_in[1];
    const float* v_f  = (const float*)d_in[2];
    const float* Wq_f = (const float*)d_in[3];
    const float* Wk_f = (const float*)d_in[4];
    const float* Wv_f = (const float*)d_in[5];
    const float* Wo_f = (const float*)d_in[6];
    const float* bo_f = (const float*)d_in[7];

    char* ws = (char*)d_ws;
    const size_t ACT = (size_t)BATCH * SEQ * DMODEL * sizeof(u16);   // 8 MB
    const size_t WSZ = (size_t)DMODEL * DMODEL * sizeof(u16);        // 2 MB
    u16* Xq  = (u16*)(ws);
    u16* Xk  = (u16*)(ws + ACT);
    u16* Xv  = (u16*)(ws + 2 * ACT);
    u16* Wqb = (u16*)(ws + 3 * ACT);
    u16* Wkb = (u16*)(ws + 3 * ACT + WSZ);
    u16* Wvb = (u16*)(ws + 3 * ACT + 2 * WSZ);
    u16* Wob = (u16*)(ws + 3 * ACT + 3 * WSZ);
    u16* Qb  = (u16*)(ws + 3 * ACT + 4 * WSZ);
    u16* Kb  = (u16*)(ws + 4 * ACT + 4 * WSZ);
    u16* Vb  = (u16*)(ws + 5 * ACT + 4 * WSZ);
    u16* AO  = (u16*)(ws + 6 * ACT + 4 * WSZ);   // total 7*ACT + 4*WSZ = 64 MB
    u16* Vt  = Xq;   // alias: Xq dead after gemm_qkv; cvt regenerates next call

    const int M = BATCH * SEQ;      // 4096
    const int Nn = DMODEL;          // 1024
    const int K = DMODEL;           // 1024

    cvt7_kernel<<<dim3(2048, 7, 1), 256, 0, stream>>>(
        q_f, k_f, v_f, Wq_f, Wk_f, Wv_f, Wo_f,
        Xq, Xk, Xv, Wqb, Wkb, Wvb, Wob);

    gemm_qkv_kernel<<<dim3(Nn / 128, M / 128, 3), 256, 0, stream>>>(
        Xq, Xk, Xv, Wqb, Wkb, Wvb, Qb, Kb, Vb, M, Nn, K);

    vtrans_kernel<<<dim3(SEQ / 64, BATCH * NHEAD, 1), 256, 0, stream>>>(Vb, Vt);

    attn_kernel<<<dim3(256, 1, 1), 512, 0, stream>>>(Qb, Kb, Vt, AO);

    gemm_out_kernel<<<dim3(Nn / 128, M / 64, 1), 256, 0, stream>>>(
        AO, Wob, bo_f, q_f, (float*)d_out, M, Nn, K);
}